// Round 7
// baseline (2321.990 us; speedup 1.0000x reference)
//
#include <hip/hip_runtime.h>

// TwoStreamNet on MI355X — f32 I/O, bf16 MFMA internals.
// R7: back to m97-proven GEMM geometry (128x128, 4 waves, 256 thr, 2 blocks/CU),
//     1-D grid with y-innermost decode (twin A-reads L2/L3-merge), split-K retuned,
//     fused f32->bf16 adjacency conversion on first use.

typedef short short8 __attribute__((ext_vector_type(8)));
typedef float floatx4 __attribute__((ext_vector_type(4)));
typedef unsigned short ushort4v __attribute__((ext_vector_type(4)));
typedef unsigned short u16;

#define DIMN 256
#define GBK 64

static const int kNV = 6144;
static const int kNF = 12288;
static const int SLAB = 768;

__device__ __forceinline__ float bf2f(u16 u) {
  union { unsigned int i; float f; } x; x.i = ((unsigned int)u) << 16; return x.f;
}
__device__ __forceinline__ u16 f2bf(float f) {
  union { float f; unsigned int i; } x; x.f = f;
  unsigned int r = x.i + 0x7fffu + ((x.i >> 16) & 1u);
  return (u16)(r >> 16);
}
__device__ __forceinline__ void gld_lds16(const void* g, void* l) {
  __builtin_amdgcn_global_load_lds((__attribute__((address_space(1))) void*)(g),
                                   (__attribute__((address_space(3))) void*)(l),
                                   16, 0, 0);
}

// ---------------- GEMM: C = Aop(M x K) * Bt(256 x K)^T ------------------------------
// 256 threads = 4 waves (2x2), 128x128 tile, per-wave 64x64 (4x4 16x16 frags).
// 1-D grid, y-innermost: d -> (y, bx, bz); n0 = y*128, m0 = bx*128, kb = bz*kchunk.
// Aop row-major [M][K] split at K1 between A0/A1. is32 operands converted in regs
// (optional cvtw side-write of bf16, y==0 only); bf16 operands via global_load_lds.
// fused=0: write bf16 split-K partials to P[z].  fused=1: full epilogue.
__global__ __launch_bounds__(256, 2)
void gemm_bf16_k(const void* __restrict__ A0, int A0is32,
                 const void* __restrict__ A1, int A1is32, int K1,
                 int lda0, int lda1, u16* __restrict__ cvtw,
                 const void* __restrict__ Bt, int Btis32, int ldb,
                 void* __restrict__ P, int M, int nx, int kchunk,
                 int fused, const float* __restrict__ bias,
                 const u16* __restrict__ addmat, int do_relu,
                 const float* __restrict__ resid,
                 float* __restrict__ outf, u16* __restrict__ out16)
{
  __shared__ __align__(16) u16 As[2][128 * GBK];   // 2 x 16 KB
  __shared__ __align__(16) u16 Bs[2][128 * GBK];   // 2 x 16 KB

  const int d = blockIdx.x;
  const int y = d & 1;
  const int bx = (d >> 1) % nx;
  const int bz = (d >> 1) / nx;
  const int m0 = bx << 7;
  const int n0 = y << 7;
  const int kb = bz * kchunk;
  const int nkt = kchunk / GBK;

  const int tid = threadIdx.x;
  const int wid = tid >> 6;        // 0..3
  const int lane = tid & 63;
  const int wr = wid >> 1, wc = wid & 1;
  const int srow = lane >> 3;      // 0..7 rows within 1KB chunk
  const int skk = (lane & 7) << 3; // 0,8,...,56 k-offset

  floatx4 acc[4][4];
  floatx4 zz = {0.f, 0.f, 0.f, 0.f};
#pragma unroll
  for (int i = 0; i < 4; ++i)
#pragma unroll
    for (int j = 0; j < 4; ++j) acc[i][j] = zz;

  auto stage = [&](int buf, int k0) {
    const void* base; int lda, is32, kl;
    if (k0 < K1) { base = A0; lda = lda0; is32 = A0is32; kl = k0; }
    else         { base = A1; lda = lda1; is32 = A1is32; kl = k0 - K1; }
    if (is32) {
      const float* F = (const float*)base;
#pragma unroll
      for (int j = 0; j < 4; ++j) {        // A tile: 16 chunks, 4 per wave
        int c = (wid << 2) + j;
        const size_t gi = (size_t)(m0 + (c << 3) + srow) * lda + kl + skk;
        floatx4 f0 = *(const floatx4*)((const float*)F + gi);
        floatx4 f1 = *(const floatx4*)((const float*)F + gi + 4);
        short8 v;
#pragma unroll
        for (int e = 0; e < 4; ++e) { v[e] = (short)f2bf(f0[e]); v[4 + e] = (short)f2bf(f1[e]); }
        *(short8*)&As[buf][(c << 9) + (lane << 3)] = v;
        if (cvtw && y == 0) *(short8*)(cvtw + gi) = v;
      }
    } else {
      const u16* U = (const u16*)base;
#pragma unroll
      for (int j = 0; j < 4; ++j) {
        int c = (wid << 2) + j;
        gld_lds16(U + (size_t)(m0 + (c << 3) + srow) * lda + kl + skk,
                  (void*)&As[buf][c << 9]);
      }
    }
    if (Btis32) {
      const float* F = (const float*)Bt;
#pragma unroll
      for (int j = 0; j < 4; ++j) {        // B tile: 16 chunks, 4 per wave
        int c = (wid << 2) + j;
        const size_t gi = (size_t)(n0 + (c << 3) + srow) * ldb + k0 + skk;
        floatx4 f0 = *(const floatx4*)((const float*)F + gi);
        floatx4 f1 = *(const floatx4*)((const float*)F + gi + 4);
        short8 v;
#pragma unroll
        for (int e = 0; e < 4; ++e) { v[e] = (short)f2bf(f0[e]); v[4 + e] = (short)f2bf(f1[e]); }
        *(short8*)&Bs[buf][(c << 9) + (lane << 3)] = v;
      }
    } else {
      const u16* U = (const u16*)Bt;
#pragma unroll
      for (int j = 0; j < 4; ++j) {
        int c = (wid << 2) + j;
        gld_lds16(U + (size_t)(n0 + (c << 3) + srow) * ldb + k0 + skk,
                  (void*)&Bs[buf][c << 9]);
      }
    }
  };

  int cur = 0;
  stage(0, kb);
  for (int kt = 0; kt < nkt; ++kt) {
    __syncthreads();  // drains vmcnt+lgkmcnt: staging of `cur` complete
    if (kt + 1 < nkt) stage(cur ^ 1, kb + (kt + 1) * GBK);
#pragma unroll
    for (int ks = 0; ks < 2; ++ks) {
      short8 a[4], b[4];
      const int ko = (ks << 5) + ((lane >> 4) << 3);
#pragma unroll
      for (int mi = 0; mi < 4; ++mi)
        a[mi] = *(const short8*)&As[cur][((wr << 6) + (mi << 4) + (lane & 15)) * GBK + ko];
#pragma unroll
      for (int ni = 0; ni < 4; ++ni)
        b[ni] = *(const short8*)&Bs[cur][((wc << 6) + (ni << 4) + (lane & 15)) * GBK + ko];
#pragma unroll
      for (int mi = 0; mi < 4; ++mi)
#pragma unroll
        for (int ni = 0; ni < 4; ++ni)
          acc[mi][ni] = __builtin_amdgcn_mfma_f32_16x16x32_bf16(a[mi], b[ni], acc[mi][ni], 0, 0, 0);
    }
    cur ^= 1;
  }

  if (fused) {
#pragma unroll
    for (int mi = 0; mi < 4; ++mi) {
#pragma unroll
      for (int ni = 0; ni < 4; ++ni) {
        const int mb = m0 + (wr << 6) + (mi << 4) + ((lane >> 4) << 2);
        const int n = n0 + (wc << 6) + (ni << 4) + (lane & 15);
        const float bv = bias ? bias[n] : 0.f;
#pragma unroll
        for (int r = 0; r < 4; ++r) {
          const size_t idx = (size_t)(mb + r) * DIMN + n;
          float t = acc[mi][ni][r] + bv;
          if (addmat) t += bf2f(addmat[idx]);
          if (do_relu) t = fmaxf(t, 0.f);
          if (resid) t += resid[idx];
          if (outf) outf[idx] = t;
          if (out16) out16[idx] = f2bf(t);
        }
      }
    }
  } else {
    u16* Pz = (u16*)P + (size_t)bz * (size_t)M * DIMN;
#pragma unroll
    for (int mi = 0; mi < 4; ++mi) {
#pragma unroll
      for (int ni = 0; ni < 4; ++ni) {
        const int mb = m0 + (wr << 6) + (mi << 4) + ((lane >> 4) << 2);
        const int n = n0 + (wc << 6) + (ni << 4) + (lane & 15);
#pragma unroll
        for (int r = 0; r < 4; ++r)
          Pz[(size_t)(mb + r) * DIMN + n] = f2bf(acc[mi][ni][r]);
      }
    }
  }
}

// ---- finalize: t = sum_s P[s](bf16)*scale; -> out (f32) and/or out16 (bf16) -------
__global__ __launch_bounds__(256)
void finalize_k(const u16* __restrict__ P, int S, int Mrows, float scale,
                float* __restrict__ out, u16* __restrict__ out16)
{
  const size_t MN = (size_t)Mrows * DIMN;
  const size_t i4 = (((size_t)blockIdx.x * blockDim.x) + threadIdx.x) * 4;
  if (i4 >= MN) return;
  floatx4 v = {0.f, 0.f, 0.f, 0.f};
  for (int s = 0; s < S; ++s) {
    ushort4v p4 = *(const ushort4v*)(P + (size_t)s * MN + i4);
#pragma unroll
    for (int j = 0; j < 4; ++j) v[j] += bf2f(p4[j]);
  }
  floatx4 o;
#pragma unroll
  for (int j = 0; j < 4; ++j) o[j] = v[j] * scale;
  if (out) *(floatx4*)(out + i4) = o;
  if (out16) {
    unsigned long long q = 0;
#pragma unroll
    for (int j = 0; j < 4; ++j) q |= ((unsigned long long)f2bf(o[j])) << (16 * j);
    *(unsigned long long*)(out16 + i4) = q;
  }
}

// -------- transpose (f32 or bf16 in, bf16 out): out[c][r] = in[r][c], 64x64 tiles --
__global__ __launch_bounds__(256)
void transpose_k(const void* __restrict__ in, int is32, int ldin,
                 u16* __restrict__ out, int ldout)
{
  __shared__ __align__(16) u16 t[64][64];
  const int c0 = blockIdx.x << 6;
  const int r0 = blockIdx.y << 6;
  const int tid = threadIdx.x;
  const int lr = tid >> 3;          // 0..31
  const int lc = (tid & 7) << 3;    // 0,8,...,56
#pragma unroll
  for (int h = 0; h < 2; ++h) {
    const int r = lr + (h << 5);
    short8 v;
    if (is32) {
      const float* F = (const float*)in;
      const float* src = F + (size_t)(r0 + r) * ldin + (c0 + lc);
      floatx4 f0 = *(const floatx4*)src;
      floatx4 f1 = *(const floatx4*)(src + 4);
#pragma unroll
      for (int e = 0; e < 4; ++e) { v[e] = (short)f2bf(f0[e]); v[4 + e] = (short)f2bf(f1[e]); }
    } else {
      v = *(const short8*)((const u16*)in + (size_t)(r0 + r) * ldin + (c0 + lc));
    }
    *(short8*)&t[r][lc ^ ((r >> 3) << 3)] = v;
  }
  __syncthreads();
#pragma unroll
  for (int h = 0; h < 2; ++h) {
    const int oc = lr + (h << 5);
    short8 v;
#pragma unroll
    for (int e = 0; e < 8; ++e)
      v[e] = (short)t[lc + e][oc ^ ((lc >> 3) << 3)];
    *(short8*)&out[(size_t)(c0 + oc) * ldout + (r0 + lc)] = v;
  }
}

// -------- f = mean_t |x_p[faces[f,t]] - x_d[f]|  (f32 in, bf16 out) ----------------
__global__ __launch_bounds__(256)
void face_gather_k(const float* __restrict__ xp, const float* __restrict__ xd,
                   const int* __restrict__ faces, u16* __restrict__ f)
{
  const int fi = blockIdx.x;
  const int j = threadIdx.x;
  const int a = faces[fi * 3 + 0];
  const int b = faces[fi * 3 + 1];
  const int c = faces[fi * 3 + 2];
  const float xv = xd[(size_t)fi * DIMN + j];
  const float s = fabsf(xp[(size_t)a * DIMN + j] - xv)
                + fabsf(xp[(size_t)b * DIMN + j] - xv)
                + fabsf(xp[(size_t)c * DIMN + j] - xv);
  f[(size_t)fi * DIMN + j] = f2bf(s * (1.0f / 3.0f));
}

extern "C" void kernel_launch(void* const* d_in, const int* in_sizes, int n_in,
                              void* d_out, int out_size, void* d_ws, size_t ws_size,
                              hipStream_t stream)
{
  (void)in_sizes; (void)n_in; (void)out_size;
  const float* primal   = (const float*)d_in[0];
  const float* A_primal = (const float*)d_in[1];
  const float* A_dual   = (const float*)d_in[2];
  const float* A        = (const float*)d_in[3];
  const int* faces      = (const int*)d_in[4];
  const float* pW  = (const float*)d_in[5];
  const float* pb  = (const float*)d_in[6];
  const float* pgW = (const float*)d_in[7];
  const float* pgb = (const float*)d_in[8];
  const float* dW  = (const float*)d_in[9];
  const float* db  = (const float*)d_in[10];
  const float* dgW = (const float*)d_in[11];
  const float* dgb = (const float*)d_in[12];
  const float* Wp  = (const float*)d_in[13];
  const float* bp  = (const float*)d_in[14];
  const float* Wd  = (const float*)d_in[15];
  const float* bd  = (const float*)d_in[16];

  char* wsp = (char*)d_ws;
  auto alloc = [&](size_t bytes) -> void* {
    void* p = (void*)wsp;
    wsp += (bytes + 255) & ~(size_t)255;
    return p;
  };
  const size_t NVD = (size_t)kNV * DIMN, NFD = (size_t)kNF * DIMN;
  // small buffers (~80 MB)
  u16* XT    = (u16*)alloc(NFD * 2);                 // x^T [256][M] bf16
  u16* TB    = (u16*)alloc((size_t)SLAB * kNV * 2);  // fc^T / f^T / A^T slab (bf16)
  u16* t1    = (u16*)alloc(NFD * 2);                 // Adj@X / Adj@fc / f (bf16)
  u16* fc    = (u16*)alloc(NFD * 2);                 // out_fc / mapped (bf16)
  u16* P     = (u16*)alloc((size_t)8 * NFD * 2);     // bf16 split-K partials 50MB
  // big bf16 operand cache (~528 MB) — used only if ws_size allows
  const size_t bigElems = (size_t)kNF * kNF + (size_t)kNF * kNV + (size_t)kNV * kNV;
  const size_t need = (size_t)(wsp - (char*)d_ws) + bigElems * 2 + 4096;
  const bool big = ws_size >= need;
  u16 *Ad16 = nullptr, *At16 = nullptr, *Ap16 = nullptr;
  if (big) {
    Ad16 = (u16*)alloc((size_t)kNF * kNF * 2);
    At16 = (u16*)alloc((size_t)kNF * kNV * 2);
    Ap16 = (u16*)alloc((size_t)kNV * kNV * 2);
  }

  float* out0  = (float*)d_out;      // out_primal + x_p
  float* out1  = out0 + NVD;         // out_dual + x_d
  float* pouts = out1 + NFD;         // primal_outs x3 (f32)
  float* douts = pouts + 3 * NVD;    // dual_outs x3 (f32)

  // split-K GEMM -> bf16 partials in P
  auto gemmP = [&](const void* A0p, int a0is32, int lda0, u16* cvtw,
                   const void* Btp, int ldb, int M, int K, int S) {
    const int nx = M / 128;
    gemm_bf16_k<<<dim3(nx * 2 * S), dim3(256), 0, stream>>>(
        A0p, a0is32, nullptr, 0, K, lda0, 0, cvtw, Btp, 0, ldb,
        P, M, nx, K / S, 0, nullptr, nullptr, 0, nullptr, nullptr, nullptr);
  };
  // fused single-pass GEMM with epilogue (B operand f32)
  auto gemmF = [&](const void* A0p, int a0is32, int lda0,
                   const void* A1p, int a1is32, int lda1, int K1,
                   const float* Btp, int ldb, int M, int K,
                   const float* bias, const u16* add, int relu,
                   const float* resid, float* outf, u16* out16) {
    const int nx = M / 128;
    gemm_bf16_k<<<dim3(nx * 2), dim3(256), 0, stream>>>(
        A0p, a0is32, A1p, a1is32, K1, lda0, lda1, nullptr, Btp, 1, ldb,
        P, M, nx, K, 1, bias, add, relu, resid, outf, out16);
  };
  auto fin = [&](int M, int S, float scale, float* out, u16* out16) {
    finalize_k<<<dim3((unsigned)((size_t)M * DIMN / 1024)), dim3(256), 0, stream>>>(
        P, S, M, scale, out, out16);
  };
  auto tranp = [&](const void* in, int is32, int ldin, u16* out, int ldout,
                   int R, int C) {
    transpose_k<<<dim3(C / 64, R / 64), dim3(256), 0, stream>>>(
        in, is32, ldin, out, ldout);
  };

  // ---- prep: XT = primal^T; pouts[0] = primal; At16 = A^T (bf16) ----
  tranp(primal, 1, DIMN, XT, kNV, kNV, DIMN);
  hipMemcpyAsync(pouts, primal, NVD * 4, hipMemcpyDeviceToDevice, stream);
  if (big) tranp(A, 1, kNF, At16, kNV, kNV, kNF);    // At16 [12288][6144]

  // ---- x_d = (1/3) A^T @ primal ----
  if (big) {
    gemmP(At16, 0, kNV, nullptr, XT, kNV, kNF, kNV, 4);
    fin(kNF, 4, 1.0f / 3.0f, douts, nullptr);
  } else {
    for (int s = 0; s < kNF / SLAB; ++s) {
      const int m0 = s * SLAB;
      tranp(A + m0, 1, kNF, TB, kNV, kNV, SLAB);
      gemmP(TB, 0, kNV, nullptr, XT, kNV, SLAB, kNV, 16);
      fin(SLAB, 16, 1.0f / 3.0f, douts + (size_t)m0 * DIMN, nullptr);
    }
  }

  // ---- primal AGG layers (x_p f32 in pouts slots / out0) ----
  const float* xpc = primal;
  for (int i = 0; i < 3; ++i) {
    if (big && i == 0)
      gemmP(A_primal, 1, kNV, Ap16, XT, kNV, kNV, kNV, 8);      // f32 read + cvt
    else
      gemmP(big ? (const void*)Ap16 : (const void*)A_primal, big ? 0 : 1,
            kNV, nullptr, XT, kNV, kNV, kNV, 8);
    fin(kNV, 8, 1.f, nullptr, t1);                              // t1 bf16
    gemmF(t1, 0, 256, nullptr, 0, 0, 256, pW + (size_t)i * 65536, 256,
          kNV, 256, pb + i * 256, nullptr, 0, nullptr, nullptr, fc);   // fc bf16
    tranp(fc, 0, DIMN, TB, kNV, kNV, DIMN);                     // fc^T
    gemmP(big ? (const void*)Ap16 : (const void*)A_primal, big ? 0 : 1,
          kNV, nullptr, TB, kNV, kNV, kNV, 8);                  // Ap@fc
    fin(kNV, 8, 1.f, nullptr, t1);
    float* nxt = (i < 2) ? (pouts + (size_t)(i + 1) * NVD) : out0;
    gemmF(t1, 0, 256, nullptr, 0, 0, 256, pgW + (size_t)i * 65536, 256,
          kNV, 256, pgb + i * 256, fc, 1, xpc, nxt, nullptr);   // relu(fc+og)+x
    xpc = nxt;
    if (i < 2) tranp(xpc, 1, DIMN, XT, kNV, kNV, DIMN);
  }

  // ---- dual AGG layers (x_d f32 in douts slots / out1) ----
  const float* xdc = douts;
  tranp(xdc, 1, DIMN, XT, kNF, kNF, DIMN);
  for (int i = 0; i < 3; ++i) {
    if (big && i == 0)
      gemmP(A_dual, 1, kNF, Ad16, XT, kNF, kNF, kNF, 4);        // f32 read + cvt
    else
      gemmP(big ? (const void*)Ad16 : (const void*)A_dual, big ? 0 : 1,
            kNF, nullptr, XT, kNF, kNF, kNF, 4);
    fin(kNF, 4, 1.f, nullptr, t1);
    gemmF(t1, 0, 256, nullptr, 0, 0, 256, dW + (size_t)i * 65536, 256,
          kNF, 256, db + i * 256, nullptr, 0, nullptr, nullptr, fc);
    tranp(fc, 0, DIMN, TB, kNF, kNF, DIMN);
    gemmP(big ? (const void*)Ad16 : (const void*)A_dual, big ? 0 : 1,
          kNF, nullptr, TB, kNF, kNF, kNF, 4);
    fin(kNF, 4, 1.f, nullptr, t1);
    float* nxt = (i < 2) ? (douts + (size_t)(i + 1) * NFD) : out1;
    gemmF(t1, 0, 256, nullptr, 0, 0, 256, dgW + (size_t)i * 65536, 256,
          kNF, 256, dgb + i * 256, fc, 1, xdc, nxt, nullptr);
    xdc = nxt;
    if (i < 2) tranp(xdc, 1, DIMN, XT, kNF, kNF, DIMN);
  }

  // ---- PDF ----
  face_gather_k<<<dim3(kNF), dim3(256), 0, stream>>>(xpc, xdc, faces, t1);  // f bf16
  tranp(t1, 0, DIMN, TB, kNF, kNF, DIMN);                                   // f^T
  // out_dual = relu([x_d, f] @ Wd^T + bd) + x_d   (in-place on out1)
  gemmF(xdc, 1, 256, t1, 0, 256, 256, Wd, 512, kNF, 512,
        bd, nullptr, 1, xdc, out1, nullptr);
  // mapped = A @ f  -> bf16 in fc   (A stays f32: single use as row-major)
  gemmP(A, 1, kNF, nullptr, TB, kNF, kNV, kNF, 8);
  fin(kNV, 8, 1.f, nullptr, fc);
  // out_primal = relu([x_p, mapped] @ Wp^T + bp) + x_p   (in-place on out0)
  gemmF(xpc, 1, 256, fc, 0, 256, 256, Wp, 512, kNV, 512,
        bp, nullptr, 1, xpc, out0, nullptr);
}

// Round 8
// 2127.141 us; speedup vs baseline: 1.0916x; 1.0916x over previous
//
#include <hip/hip_runtime.h>

// TwoStreamNet on MI355X — f32 I/O, bf16 MFMA internals.
// R8: all adjacency GEMMs on the bf16 global_load_lds path (m97 geometry);
//     dedicated streaming f32->bf16 conversion kernels (A_dual, A_primal);
//     single pass over A emits both A^T(bf16) and A(bf16).

typedef short short8 __attribute__((ext_vector_type(8)));
typedef float floatx4 __attribute__((ext_vector_type(4)));
typedef unsigned short ushort4v __attribute__((ext_vector_type(4)));
typedef unsigned short u16;

#define DIMN 256
#define GBK 64

static const int kNV = 6144;
static const int kNF = 12288;
static const int SLAB = 768;

__device__ __forceinline__ float bf2f(u16 u) {
  union { unsigned int i; float f; } x; x.i = ((unsigned int)u) << 16; return x.f;
}
__device__ __forceinline__ u16 f2bf(float f) {
  union { float f; unsigned int i; } x; x.f = f;
  unsigned int r = x.i + 0x7fffu + ((x.i >> 16) & 1u);
  return (u16)(r >> 16);
}
__device__ __forceinline__ void gld_lds16(const void* g, void* l) {
  __builtin_amdgcn_global_load_lds((__attribute__((address_space(1))) void*)(g),
                                   (__attribute__((address_space(3))) void*)(l),
                                   16, 0, 0);
}

// ---------------- GEMM: C = Aop(M x K) * Bt(256 x K)^T ------------------------------
// 256 threads = 4 waves (2x2), 128x128 tile, per-wave 64x64 (4x4 16x16 frags).
// 1-D grid, y-innermost: d -> (y, bx, bz); n0 = y*128, m0 = bx*128, kb = bz*kchunk.
// Aop row-major [M][K] split at K1 between A0/A1. is32 operands converted in regs;
// bf16 operands staged via global_load_lds (the fast path — use it for all big ops).
// fused=0: write bf16 split-K partials to P[bz].  fused=1: full epilogue.
__global__ __launch_bounds__(256, 2)
void gemm_bf16_k(const void* __restrict__ A0, int A0is32,
                 const void* __restrict__ A1, int A1is32, int K1,
                 int lda0, int lda1,
                 const void* __restrict__ Bt, int Btis32, int ldb,
                 void* __restrict__ P, int M, int nx, int kchunk,
                 int fused, const float* __restrict__ bias,
                 const u16* __restrict__ addmat, int do_relu,
                 const float* __restrict__ resid,
                 float* __restrict__ outf, u16* __restrict__ out16)
{
  __shared__ __align__(16) u16 As[2][128 * GBK];   // 2 x 16 KB
  __shared__ __align__(16) u16 Bs[2][128 * GBK];   // 2 x 16 KB

  const int d = blockIdx.x;
  const int y = d & 1;
  const int bx = (d >> 1) % nx;
  const int bz = (d >> 1) / nx;
  const int m0 = bx << 7;
  const int n0 = y << 7;
  const int kb = bz * kchunk;
  const int nkt = kchunk / GBK;

  const int tid = threadIdx.x;
  const int wid = tid >> 6;        // 0..3
  const int lane = tid & 63;
  const int wr = wid >> 1, wc = wid & 1;
  const int srow = lane >> 3;      // 0..7 rows within 1KB chunk
  const int skk = (lane & 7) << 3; // 0,8,...,56 k-offset

  floatx4 acc[4][4];
  floatx4 zz = {0.f, 0.f, 0.f, 0.f};
#pragma unroll
  for (int i = 0; i < 4; ++i)
#pragma unroll
    for (int j = 0; j < 4; ++j) acc[i][j] = zz;

  auto stage = [&](int buf, int k0) {
    const void* base; int lda, is32, kl;
    if (k0 < K1) { base = A0; lda = lda0; is32 = A0is32; kl = k0; }
    else         { base = A1; lda = lda1; is32 = A1is32; kl = k0 - K1; }
    if (is32) {
      const float* F = (const float*)base;
#pragma unroll
      for (int j = 0; j < 4; ++j) {        // A tile: 16 chunks, 4 per wave
        int c = (wid << 2) + j;
        const size_t gi = (size_t)(m0 + (c << 3) + srow) * lda + kl + skk;
        floatx4 f0 = *(const floatx4*)(F + gi);
        floatx4 f1 = *(const floatx4*)(F + gi + 4);
        short8 v;
#pragma unroll
        for (int e = 0; e < 4; ++e) { v[e] = (short)f2bf(f0[e]); v[4 + e] = (short)f2bf(f1[e]); }
        *(short8*)&As[buf][(c << 9) + (lane << 3)] = v;
      }
    } else {
      const u16* U = (const u16*)base;
#pragma unroll
      for (int j = 0; j < 4; ++j) {
        int c = (wid << 2) + j;
        gld_lds16(U + (size_t)(m0 + (c << 3) + srow) * lda + kl + skk,
                  (void*)&As[buf][c << 9]);
      }
    }
    if (Btis32) {
      const float* F = (const float*)Bt;
#pragma unroll
      for (int j = 0; j < 4; ++j) {        // B tile: 16 chunks, 4 per wave
        int c = (wid << 2) + j;
        const size_t gi = (size_t)(n0 + (c << 3) + srow) * ldb + k0 + skk;
        floatx4 f0 = *(const floatx4*)(F + gi);
        floatx4 f1 = *(const floatx4*)(F + gi + 4);
        short8 v;
#pragma unroll
        for (int e = 0; e < 4; ++e) { v[e] = (short)f2bf(f0[e]); v[4 + e] = (short)f2bf(f1[e]); }
        *(short8*)&Bs[buf][(c << 9) + (lane << 3)] = v;
      }
    } else {
      const u16* U = (const u16*)Bt;
#pragma unroll
      for (int j = 0; j < 4; ++j) {
        int c = (wid << 2) + j;
        gld_lds16(U + (size_t)(n0 + (c << 3) + srow) * ldb + k0 + skk,
                  (void*)&Bs[buf][c << 9]);
      }
    }
  };

  int cur = 0;
  stage(0, kb);
  for (int kt = 0; kt < nkt; ++kt) {
    __syncthreads();  // drains vmcnt+lgkmcnt: staging of `cur` complete
    if (kt + 1 < nkt) stage(cur ^ 1, kb + (kt + 1) * GBK);
#pragma unroll
    for (int ks = 0; ks < 2; ++ks) {
      short8 a[4], b[4];
      const int ko = (ks << 5) + ((lane >> 4) << 3);
#pragma unroll
      for (int mi = 0; mi < 4; ++mi)
        a[mi] = *(const short8*)&As[cur][((wr << 6) + (mi << 4) + (lane & 15)) * GBK + ko];
#pragma unroll
      for (int ni = 0; ni < 4; ++ni)
        b[ni] = *(const short8*)&Bs[cur][((wc << 6) + (ni << 4) + (lane & 15)) * GBK + ko];
#pragma unroll
      for (int mi = 0; mi < 4; ++mi)
#pragma unroll
        for (int ni = 0; ni < 4; ++ni)
          acc[mi][ni] = __builtin_amdgcn_mfma_f32_16x16x32_bf16(a[mi], b[ni], acc[mi][ni], 0, 0, 0);
    }
    cur ^= 1;
  }

  if (fused) {
#pragma unroll
    for (int mi = 0; mi < 4; ++mi) {
#pragma unroll
      for (int ni = 0; ni < 4; ++ni) {
        const int mb = m0 + (wr << 6) + (mi << 4) + ((lane >> 4) << 2);
        const int n = n0 + (wc << 6) + (ni << 4) + (lane & 15);
        const float bv = bias ? bias[n] : 0.f;
#pragma unroll
        for (int r = 0; r < 4; ++r) {
          const size_t idx = (size_t)(mb + r) * DIMN + n;
          float t = acc[mi][ni][r] + bv;
          if (addmat) t += bf2f(addmat[idx]);
          if (do_relu) t = fmaxf(t, 0.f);
          if (resid) t += resid[idx];
          if (outf) outf[idx] = t;
          if (out16) out16[idx] = f2bf(t);
        }
      }
    }
  } else {
    u16* Pz = (u16*)P + (size_t)bz * (size_t)M * DIMN;
#pragma unroll
    for (int mi = 0; mi < 4; ++mi) {
#pragma unroll
      for (int ni = 0; ni < 4; ++ni) {
        const int mb = m0 + (wr << 6) + (mi << 4) + ((lane >> 4) << 2);
        const int n = n0 + (wc << 6) + (ni << 4) + (lane & 15);
#pragma unroll
        for (int r = 0; r < 4; ++r)
          Pz[(size_t)(mb + r) * DIMN + n] = f2bf(acc[mi][ni][r]);
      }
    }
  }
}

// ---- finalize: t = sum_s P[s](bf16)*scale; -> out (f32) and/or out16 (bf16) -------
__global__ __launch_bounds__(256)
void finalize_k(const u16* __restrict__ P, int S, int Mrows, float scale,
                float* __restrict__ out, u16* __restrict__ out16)
{
  const size_t MN = (size_t)Mrows * DIMN;
  const size_t i4 = (((size_t)blockIdx.x * blockDim.x) + threadIdx.x) * 4;
  if (i4 >= MN) return;
  floatx4 v = {0.f, 0.f, 0.f, 0.f};
  for (int s = 0; s < S; ++s) {
    ushort4v p4 = *(const ushort4v*)(P + (size_t)s * MN + i4);
#pragma unroll
    for (int j = 0; j < 4; ++j) v[j] += bf2f(p4[j]);
  }
  floatx4 o;
#pragma unroll
  for (int j = 0; j < 4; ++j) o[j] = v[j] * scale;
  if (out) *(floatx4*)(out + i4) = o;
  if (out16) {
    unsigned long long q = 0;
#pragma unroll
    for (int j = 0; j < 4; ++j) q |= ((unsigned long long)f2bf(o[j])) << (16 * j);
    *(unsigned long long*)(out16 + i4) = q;
  }
}

// -------- transpose (f32 or bf16 in, bf16 out): out[c][r] = in[r][c], 64x64 tiles --
// When is32 and copy16 != null, also emits the straight (non-transposed) bf16 copy.
__global__ __launch_bounds__(256)
void transpose_k(const void* __restrict__ in, int is32, int ldin,
                 u16* __restrict__ out, int ldout, u16* __restrict__ copy16)
{
  __shared__ __align__(16) u16 t[64][64];
  const int c0 = blockIdx.x << 6;
  const int r0 = blockIdx.y << 6;
  const int tid = threadIdx.x;
  const int lr = tid >> 3;          // 0..31
  const int lc = (tid & 7) << 3;    // 0,8,...,56
#pragma unroll
  for (int h = 0; h < 2; ++h) {
    const int r = lr + (h << 5);
    short8 v;
    if (is32) {
      const float* F = (const float*)in;
      const size_t gi = (size_t)(r0 + r) * ldin + (c0 + lc);
      floatx4 f0 = *(const floatx4*)(F + gi);
      floatx4 f1 = *(const floatx4*)(F + gi + 4);
#pragma unroll
      for (int e = 0; e < 4; ++e) { v[e] = (short)f2bf(f0[e]); v[4 + e] = (short)f2bf(f1[e]); }
      if (copy16) *(short8*)(copy16 + gi) = v;
    } else {
      v = *(const short8*)((const u16*)in + (size_t)(r0 + r) * ldin + (c0 + lc));
    }
    *(short8*)&t[r][lc ^ ((r >> 3) << 3)] = v;
  }
  __syncthreads();
#pragma unroll
  for (int h = 0; h < 2; ++h) {
    const int oc = lr + (h << 5);
    short8 v;
#pragma unroll
    for (int e = 0; e < 8; ++e)
      v[e] = (short)t[lc + e][oc ^ ((lc >> 3) << 3)];
    *(short8*)&out[(size_t)(c0 + oc) * ldout + (r0 + lc)] = v;
  }
}

// -------- elementwise f32 -> bf16 convert (8 elems/thread, grid-stride) -------------
__global__ __launch_bounds__(256)
void cvt8_k(const float* __restrict__ in, u16* __restrict__ out, size_t n)
{
  const size_t stride = (size_t)gridDim.x * 2048;
  for (size_t i = (((size_t)blockIdx.x << 8) + threadIdx.x) << 3; i < n; i += stride) {
    floatx4 f0 = *(const floatx4*)(in + i);
    floatx4 f1 = *(const floatx4*)(in + i + 4);
    short8 v;
#pragma unroll
    for (int e = 0; e < 4; ++e) { v[e] = (short)f2bf(f0[e]); v[4 + e] = (short)f2bf(f1[e]); }
    *(short8*)(out + i) = v;
  }
}

// -------- f = mean_t |x_p[faces[f,t]] - x_d[f]|  (f32 in, bf16 out) ----------------
__global__ __launch_bounds__(256)
void face_gather_k(const float* __restrict__ xp, const float* __restrict__ xd,
                   const int* __restrict__ faces, u16* __restrict__ f)
{
  const int fi = blockIdx.x;
  const int j = threadIdx.x;
  const int a = faces[fi * 3 + 0];
  const int b = faces[fi * 3 + 1];
  const int c = faces[fi * 3 + 2];
  const float xv = xd[(size_t)fi * DIMN + j];
  const float s = fabsf(xp[(size_t)a * DIMN + j] - xv)
                + fabsf(xp[(size_t)b * DIMN + j] - xv)
                + fabsf(xp[(size_t)c * DIMN + j] - xv);
  f[(size_t)fi * DIMN + j] = f2bf(s * (1.0f / 3.0f));
}

extern "C" void kernel_launch(void* const* d_in, const int* in_sizes, int n_in,
                              void* d_out, int out_size, void* d_ws, size_t ws_size,
                              hipStream_t stream)
{
  (void)in_sizes; (void)n_in; (void)out_size;
  const float* primal   = (const float*)d_in[0];
  const float* A_primal = (const float*)d_in[1];
  const float* A_dual   = (const float*)d_in[2];
  const float* A        = (const float*)d_in[3];
  const int* faces      = (const int*)d_in[4];
  const float* pW  = (const float*)d_in[5];
  const float* pb  = (const float*)d_in[6];
  const float* pgW = (const float*)d_in[7];
  const float* pgb = (const float*)d_in[8];
  const float* dW  = (const float*)d_in[9];
  const float* db  = (const float*)d_in[10];
  const float* dgW = (const float*)d_in[11];
  const float* dgb = (const float*)d_in[12];
  const float* Wp  = (const float*)d_in[13];
  const float* bp  = (const float*)d_in[14];
  const float* Wd  = (const float*)d_in[15];
  const float* bd  = (const float*)d_in[16];

  char* wsp = (char*)d_ws;
  auto alloc = [&](size_t bytes) -> void* {
    void* p = (void*)wsp;
    wsp += (bytes + 255) & ~(size_t)255;
    return p;
  };
  const size_t NVD = (size_t)kNV * DIMN, NFD = (size_t)kNF * DIMN;
  // small buffers (~80 MB)
  u16* XT    = (u16*)alloc(NFD * 2);                 // x^T [256][M] bf16
  u16* TB    = (u16*)alloc((size_t)SLAB * kNV * 2);  // fc^T / f^T / A^T slab (bf16)
  u16* t1    = (u16*)alloc(NFD * 2);                 // Adj@X / Adj@fc / f (bf16)
  u16* fc    = (u16*)alloc(NFD * 2);                 // out_fc / mapped (bf16)
  u16* P     = (u16*)alloc((size_t)8 * NFD * 2);     // bf16 split-K partials 50MB
  // big bf16 operand cache (~680 MB) — used only if ws_size allows (~2.25GB avail)
  const size_t bigElems = (size_t)kNF * kNF + 2 * (size_t)kNF * kNV + (size_t)kNV * kNV;
  const size_t need = (size_t)(wsp - (char*)d_ws) + bigElems * 2 + 4096;
  const bool big = ws_size >= need;
  u16 *Ad16 = nullptr, *At16 = nullptr, *A16 = nullptr, *Ap16 = nullptr;
  if (big) {
    Ad16 = (u16*)alloc((size_t)kNF * kNF * 2);       // A_dual bf16   302MB
    At16 = (u16*)alloc((size_t)kNF * kNV * 2);       // A^T bf16      151MB
    A16  = (u16*)alloc((size_t)kNV * kNF * 2);       // A bf16        151MB
    Ap16 = (u16*)alloc((size_t)kNV * kNV * 2);       // A_primal bf16  75MB
  }

  float* out0  = (float*)d_out;      // out_primal + x_p
  float* out1  = out0 + NVD;         // out_dual + x_d
  float* pouts = out1 + NFD;         // primal_outs x3 (f32)
  float* douts = pouts + 3 * NVD;    // dual_outs x3 (f32)

  // split-K GEMM -> bf16 partials in P
  auto gemmP = [&](const void* A0p, int a0is32, int lda0,
                   const void* Btp, int ldb, int M, int K, int S) {
    const int nx = M / 128;
    gemm_bf16_k<<<dim3(nx * 2 * S), dim3(256), 0, stream>>>(
        A0p, a0is32, nullptr, 0, K, lda0, 0, Btp, 0, ldb,
        P, M, nx, K / S, 0, nullptr, nullptr, 0, nullptr, nullptr, nullptr);
  };
  // fused single-pass GEMM with epilogue (B operand f32)
  auto gemmF = [&](const void* A0p, int a0is32, int lda0,
                   const void* A1p, int a1is32, int lda1, int K1,
                   const float* Btp, int ldb, int M, int K,
                   const float* bias, const u16* add, int relu,
                   const float* resid, float* outf, u16* out16) {
    const int nx = M / 128;
    gemm_bf16_k<<<dim3(nx * 2), dim3(256), 0, stream>>>(
        A0p, a0is32, A1p, a1is32, K1, lda0, lda1, Btp, 1, ldb,
        P, M, nx, K, 1, bias, add, relu, resid, outf, out16);
  };
  auto fin = [&](int M, int S, float scale, float* out, u16* out16) {
    finalize_k<<<dim3((unsigned)((size_t)M * DIMN / 1024)), dim3(256), 0, stream>>>(
        P, S, M, scale, out, out16);
  };
  auto tranp = [&](const void* in, int is32, int ldin, u16* out, int ldout,
                   int R, int C, u16* copy16) {
    transpose_k<<<dim3(C / 64, R / 64), dim3(256), 0, stream>>>(
        in, is32, ldin, out, ldout, copy16);
  };
  auto cvt = [&](const float* in, u16* out, size_t n) {
    cvt8_k<<<dim3(2048), dim3(256), 0, stream>>>(in, out, n);
  };

  // ---- one-time operand prep (streaming conversions on the fast path) ----
  if (big) {
    cvt(A_dual, Ad16, (size_t)kNF * kNF);
    cvt(A_primal, Ap16, (size_t)kNV * kNV);
    tranp(A, 1, kNF, At16, kNV, kNV, kNF, A16);      // At16 + A16 in one pass over A
  }

  // ---- prep: XT = primal^T; pouts[0] = primal ----
  tranp(primal, 1, DIMN, XT, kNV, kNV, DIMN, nullptr);
  hipMemcpyAsync(pouts, primal, NVD * 4, hipMemcpyDeviceToDevice, stream);

  // ---- x_d = (1/3) A^T @ primal ----
  if (big) {
    gemmP(At16, 0, kNV, XT, kNV, kNF, kNV, 4);
    fin(kNF, 4, 1.0f / 3.0f, douts, nullptr);
  } else {
    for (int s = 0; s < kNF / SLAB; ++s) {
      const int m0 = s * SLAB;
      tranp(A + m0, 1, kNF, TB, kNV, kNV, SLAB, nullptr);
      gemmP(TB, 0, kNV, XT, kNV, SLAB, kNV, 16);
      fin(SLAB, 16, 1.0f / 3.0f, douts + (size_t)m0 * DIMN, nullptr);
    }
  }

  // ---- primal AGG layers (x_p f32 in pouts slots / out0) ----
  const void* ApP = big ? (const void*)Ap16 : (const void*)A_primal;
  const int apf = big ? 0 : 1;
  const float* xpc = primal;
  for (int i = 0; i < 3; ++i) {
    gemmP(ApP, apf, kNV, XT, kNV, kNV, kNV, 8);                 // Ap@X
    fin(kNV, 8, 1.f, nullptr, t1);                              // t1 bf16
    gemmF(t1, 0, 256, nullptr, 0, 0, 256, pW + (size_t)i * 65536, 256,
          kNV, 256, pb + i * 256, nullptr, 0, nullptr, nullptr, fc);   // fc bf16
    tranp(fc, 0, DIMN, TB, kNV, kNV, DIMN, nullptr);            // fc^T
    gemmP(ApP, apf, kNV, TB, kNV, kNV, kNV, 8);                 // Ap@fc
    fin(kNV, 8, 1.f, nullptr, t1);
    float* nxt = (i < 2) ? (pouts + (size_t)(i + 1) * NVD) : out0;
    gemmF(t1, 0, 256, nullptr, 0, 0, 256, pgW + (size_t)i * 65536, 256,
          kNV, 256, pgb + i * 256, fc, 1, xpc, nxt, nullptr);   // relu(fc+og)+x
    xpc = nxt;
    if (i < 2) tranp(xpc, 1, DIMN, XT, kNV, kNV, DIMN, nullptr);
  }

  // ---- dual AGG layers (x_d f32 in douts slots / out1) ----
  const void* AdP = big ? (const void*)Ad16 : (const void*)A_dual;
  const int adf = big ? 0 : 1;
  const float* xdc = douts;
  tranp(xdc, 1, DIMN, XT, kNF, kNF, DIMN, nullptr);
  for (int i = 0; i < 3; ++i) {
    gemmP(AdP, adf, kNF, XT, kNF, kNF, kNF, 4);
    fin(kNF, 4, 1.f, nullptr, t1);
    gemmF(t1, 0, 256, nullptr, 0, 0, 256, dW + (size_t)i * 65536, 256,
          kNF, 256, db + i * 256, nullptr, 0, nullptr, nullptr, fc);
    tranp(fc, 0, DIMN, TB, kNF, kNF, DIMN, nullptr);
    gemmP(AdP, adf, kNF, TB, kNF, kNF, kNF, 4);
    fin(kNF, 4, 1.f, nullptr, t1);
    float* nxt = (i < 2) ? (douts + (size_t)(i + 1) * NFD) : out1;
    gemmF(t1, 0, 256, nullptr, 0, 0, 256, dgW + (size_t)i * 65536, 256,
          kNF, 256, dgb + i * 256, fc, 1, xdc, nxt, nullptr);
    xdc = nxt;
    if (i < 2) tranp(xdc, 1, DIMN, XT, kNF, kNF, DIMN, nullptr);
  }

  // ---- PDF ----
  face_gather_k<<<dim3(kNF), dim3(256), 0, stream>>>(xpc, xdc, faces, t1);  // f bf16
  tranp(t1, 0, DIMN, TB, kNF, kNF, DIMN, nullptr);                          // f^T
  // out_dual = relu([x_d, f] @ Wd^T + bd) + x_d   (in-place on out1)
  gemmF(xdc, 1, 256, t1, 0, 256, 256, Wd, 512, kNF, 512,
        bd, nullptr, 1, xdc, out1, nullptr);
  // mapped = A @ f  -> bf16 in fc
  if (big) gemmP(A16, 0, kNF, TB, kNF, kNV, kNF, 8);
  else     gemmP(A, 1, kNF, TB, kNF, kNV, kNF, 8);
  fin(kNV, 8, 1.f, nullptr, fc);
  // out_primal = relu([x_p, mapped] @ Wp^T + bp) + x_p   (in-place on out0)
  gemmF(xpc, 1, 256, fc, 0, 256, 256, Wp, 512, kNV, 512,
        bp, nullptr, 1, xpc, out0, nullptr);
}